// Round 10
// baseline (415.891 us; speedup 1.0000x reference)
//
#include <hip/hip_runtime.h>
#include <hip/hip_bf16.h>
#include <math.h>

#define NEG_SLOPE 0.2f
#define CSRG 256     // blocks in the fused CSR kernel (capacity-co-resident)

typedef __attribute__((ext_vector_type(8))) short short8;
typedef __attribute__((ext_vector_type(4))) float floatx4;
typedef __attribute__((ext_vector_type(2))) float floatx2;

__device__ inline ushort f2b(float f) {
    __hip_bfloat16 b = __float2bfloat16(f);
    return *(ushort*)&b;
}
// dword holding 2 bf16 (lo, hi) -> floatx2
__device__ inline floatx2 bf2x2(unsigned int d) {
    union { unsigned int i; float f; } lo, hi;
    lo.i = d << 16;
    hi.i = d & 0xffff0000u;
    floatx2 r = {lo.f, hi.f};
    return r;
}

// ---------------------------------------------------------------------------
// bf16 MFMA GEMM (r9 form): C[M,N] = A[M,K] @ Bt[N,K]^T, all bf16 row-major.
// Padded LDS (SA=40), K-template unroll, hoisted staging pointers.
// ---------------------------------------------------------------------------
template<int BM, int BN, int KTOT>
__global__ __launch_bounds__(256) void gemm_bf16(const ushort* __restrict__ A,
                                                 const ushort* __restrict__ Bt,
                                                 ushort* __restrict__ C,
                                                 int M, int N)
{
    constexpr int SA = 40;
    constexpr int WTM = (BN == 64) ? 32 : 64;
    constexpr int WM  = BM / WTM;
    constexpr int IT  = WTM / 16;
    constexpr int JT  = 4;
    __shared__ ushort As[BM * SA];
    __shared__ ushort Bs[BN * SA];
    const int tid = threadIdx.x;
    const int w = tid >> 6, lane = tid & 63;
    const int mw = (w % WM) * WTM;
    const int nw = (w / WM) * 64;
    const int m0 = blockIdx.y * BM;
    const int n0 = blockIdx.x * BN;
    const int lm = lane & 15;
    const int kg = lane >> 4;
    const int srow = tid >> 2, skc = tid & 3;

    const ushort* aSrc[BM / 64];
#pragma unroll
    for (int it = 0; it < BM / 64; ++it) {
        int grow = m0 + it * 64 + srow;
        if (grow >= M) grow = M - 1;
        aSrc[it] = A + (size_t)grow * KTOT + skc * 8;
    }
    const ushort* bSrc[BN / 64];
#pragma unroll
    for (int it = 0; it < BN / 64; ++it)
        bSrc[it] = Bt + (size_t)(n0 + it * 64 + srow) * KTOT + skc * 8;

    floatx4 acc[IT][JT];
#pragma unroll
    for (int i = 0; i < IT; ++i)
#pragma unroll
        for (int j = 0; j < JT; ++j) acc[i][j] = (floatx4)0.f;

#pragma unroll
    for (int k0 = 0; k0 < KTOT; k0 += 32) {
#pragma unroll
        for (int it = 0; it < BM / 64; ++it) {
            short8 v = *(const short8*)(aSrc[it] + k0);
            *(short8*)&As[(it * 64 + srow) * SA + skc * 8] = v;
        }
#pragma unroll
        for (int it = 0; it < BN / 64; ++it) {
            short8 v = *(const short8*)(bSrc[it] + k0);
            *(short8*)&Bs[(it * 64 + srow) * SA + skc * 8] = v;
        }
        __syncthreads();
        short8 a[IT], b[JT];
#pragma unroll
        for (int i = 0; i < IT; ++i)
            a[i] = *(const short8*)&As[(mw + i * 16 + lm) * SA + kg * 8];
#pragma unroll
        for (int j = 0; j < JT; ++j)
            b[j] = *(const short8*)&Bs[(nw + j * 16 + lm) * SA + kg * 8];
#pragma unroll
        for (int i = 0; i < IT; ++i)
#pragma unroll
            for (int j = 0; j < JT; ++j)
                acc[i][j] = __builtin_amdgcn_mfma_f32_16x16x32_bf16(a[i], b[j], acc[i][j], 0, 0, 0);
        __syncthreads();
    }

#pragma unroll
    for (int i = 0; i < IT; ++i) {
        int rbase = m0 + mw + i * 16 + (lane >> 4) * 4;
#pragma unroll
        for (int j = 0; j < JT; ++j) {
            int col = n0 + nw + j * 16 + lm;
#pragma unroll
            for (int r = 0; r < 4; ++r) {
                int row = rbase + r;
                if (row < M) C[(size_t)row * N + col] = f2b(acc[i][j][r]);
            }
        }
    }
}

// ---------------------------------------------------------------------------
// Prep: x fp32->bf16 cast + 4 weight transposes/casts (no more count tail).
// ---------------------------------------------------------------------------
__global__ void k_prep(const float* __restrict__ x, ushort* __restrict__ xb, int XB,
                       const float* __restrict__ Wl1, const float* __restrict__ Wr1,
                       const float* __restrict__ Wl2, const float* __restrict__ Wr2,
                       ushort* __restrict__ wlr1t, ushort* __restrict__ wlr2t)
{
    const int b = blockIdx.x;
    const int t = threadIdx.x;
    if (b < XB) {                                 // x cast: 8 floats/thread
        int i = b * 2048 + t * 8;
        float4 f0 = *(const float4*)&x[i];
        float4 f1 = *(const float4*)&x[i + 4];
        short8 o;
        o[0] = (short)f2b(f0.x); o[1] = (short)f2b(f0.y);
        o[2] = (short)f2b(f0.z); o[3] = (short)f2b(f0.w);
        o[4] = (short)f2b(f1.x); o[5] = (short)f2b(f1.y);
        o[6] = (short)f2b(f1.z); o[7] = (short)f2b(f1.w);
        *(short8*)&xb[i] = o;
    } else {                                      // 163840 weight elements
        int i = (b - XB) * 256 + t;
        if (i < 65536) {
            int k = i >> 8, n = i & 255;
            wlr1t[n * 256 + k] = f2b(Wl1[i]);
        } else if (i < 131072) {
            int j = i - 65536;
            int k = j >> 8, n = j & 255;
            wlr1t[65536 + n * 256 + k] = f2b(Wr1[j]);
        } else if (i < 147456) {
            int j = i - 131072;
            int k = j >> 6, n = j & 63;
            wlr2t[n * 256 + k] = f2b(Wl2[j]);
        } else {
            int j = i - 147456;
            int k = j >> 6, n = j & 63;
            wlr2t[16384 + n * 256 + k] = f2b(Wr2[j]);
        }
    }
}

// ---------------------------------------------------------------------------
// Fused CSR build: ONE dispatch, CSRG=256 blocks (capacity co-resident),
// device-scope spin grid-barriers between phases:
//   zero counts -> count -> chunk sums -> scan+offsets/cursor -> fill.
// counts16/cursor16 line-strided (one counter per 64 B line).
// bar[0..3] must be zeroed before launch (16 B memset).
// ---------------------------------------------------------------------------
__device__ __forceinline__ void gbar(int* ctr, int target)
{
    __syncthreads();
    if (threadIdx.x == 0) {
        __threadfence();   // flush this XCD's prior stores to the coherent point
        __hip_atomic_fetch_add(ctr, 1, __ATOMIC_ACQ_REL, __HIP_MEMORY_SCOPE_AGENT);
        while (__hip_atomic_load(ctr, __ATOMIC_ACQUIRE, __HIP_MEMORY_SCOPE_AGENT) < target)
            __builtin_amdgcn_s_sleep(2);
    }
    __syncthreads();
}

__global__ __launch_bounds__(256) void k_csr(const int* __restrict__ src,
                                             const int* __restrict__ dst,
                                             int E, int N,
                                             int* __restrict__ counts16,
                                             int* __restrict__ cursor16,
                                             int* __restrict__ offsets,
                                             int* __restrict__ chunksum,
                                             int* __restrict__ bar,
                                             int* __restrict__ csr_off)
{
    const int t = threadIdx.x, b = blockIdx.x;
    const int gtid = b * 256 + t;
    const int GT = CSRG * 256;
    __shared__ int sm[256];

    // phase 0: zero counts16 (N*16 ints = N*4 int4s)
    {
        int4* p = (int4*)counts16;
        const int tot4 = N * 4;
        int4 z = make_int4(0, 0, 0, 0);
        for (int i = gtid; i < tot4; i += GT) p[i] = z;
    }
    gbar(&bar[0], CSRG);

    // phase 1: degree count
    for (int i = gtid; i < E; i += GT)
        __hip_atomic_fetch_add(&counts16[dst[i] * 16], 1,
                               __ATOMIC_RELAXED, __HIP_MEMORY_SCOPE_AGENT);
    gbar(&bar[1], CSRG);

    // phase 2: per-block chunk sum (CH nodes per block, CH <= 256)
    const int CH = (N + CSRG - 1) / CSRG;
    const int n = b * CH + t;
    int v = (t < CH && n < N) ? counts16[n * 16] : 0;
    sm[t] = v;
    __syncthreads();
    for (int off = 128; off; off >>= 1) {
        if (t < off) sm[t] += sm[t + off];
        __syncthreads();
    }
    if (t == 0) chunksum[b] = sm[0];
    gbar(&bar[2], CSRG);

    // phase 3: cross-block prefix (redundant per block) + local scan + write
    int cv = chunksum[t];
    sm[t] = cv;
    __syncthreads();
    for (int off = 1; off < 256; off <<= 1) {
        int y = (t >= off) ? sm[t - off] : 0;
        __syncthreads();
        sm[t] += y;
        __syncthreads();
    }
    const int total = sm[255];
    const int base = (b == 0) ? 0 : sm[b - 1];
    __syncthreads();
    sm[t] = v;
    __syncthreads();
    for (int off = 1; off < 256; off <<= 1) {
        int y = (t >= off) ? sm[t - off] : 0;
        __syncthreads();
        sm[t] += y;
        __syncthreads();
    }
    int excl = base + sm[t] - v;
    if (t < CH && n < N) {
        offsets[n] = excl;
        cursor16[n * 16] = excl;
    }
    if (b == CSRG - 1 && t == 0) offsets[N] = total;
    gbar(&bar[3], CSRG);

    // phase 4: slot fill (byte offsets into xlr1 rows; agg2 uses >>2)
    for (int i = gtid; i < E; i += GT) {
        int d = dst[i];
        int pos = __hip_atomic_fetch_add(&cursor16[d * 16], 1,
                                         __ATOMIC_RELAXED, __HIP_MEMORY_SCOPE_AGENT);
        csr_off[pos] = src[i] * 1024;
    }
    if (gtid < 16) csr_off[E + gtid] = 0;   // pad: branchless agg prefetch
}

// ---------------------------------------------------------------------------
// Layer-1 aggregation (unchanged r9): one wave per node, 2 slots x 32 lanes,
// 8 ch/lane, branchless depth-2 prefetch, packed fp32, single-exp softmax.
// xlr: row 1024 B (xl at +0, xr at +512 B).
// ---------------------------------------------------------------------------
__global__ __launch_bounds__(256) void agg1(const ushort* __restrict__ xlr,
                                            const float* __restrict__ att,
                                            const float* __restrict__ bias,
                                            const int* __restrict__ offsets,
                                            const int* __restrict__ csr_off,
                                            ushort* __restrict__ h1, int N)
{
    const int wave = blockIdx.x * 4 + (threadIdx.x >> 6);
    const int lane = threadIdx.x & 63;
    if (wave >= N) return;
    const int n = wave;
    const int g = lane >> 5;
    const int sl = lane & 31;
    const int elem = (sl >> 2) * 32 + (sl & 3) * 8;
    const char* __restrict__ xbase = (const char*)xlr;
    const int ebyte = elem * 2;

    floatx2 attv2[4], xrv2[4];
    {
        uint4 xr8 = *(const uint4*)(xbase + (size_t)n * 1024 + 512 + ebyte);
        unsigned int xw[4] = {xr8.x, xr8.y, xr8.z, xr8.w};
#pragma unroll
        for (int i = 0; i < 4; ++i) {
            attv2[i] = *(const floatx2*)&att[elem + 2 * i];
            xrv2[i] = bf2x2(xw[i]);
        }
    }
    float m = -1e30f, l = 0.f;
    floatx2 acc2[4] = {(floatx2)0.f, (floatx2)0.f, (floatx2)0.f, (floatx2)0.f};

    const int beg = offsets[n], end = offsets[n + 1];
    uint4 vA, vB;
    int oC;
    {
        int k0 = beg + g;
        vA = *(const uint4*)(xbase + (unsigned)csr_off[k0] + ebyte);
        vB = *(const uint4*)(xbase + (unsigned)csr_off[k0 + 2] + ebyte);
        oC = csr_off[k0 + 4];
    }
    for (int kk = beg + g; kk < end; kk += 2) {
        uint4 cur = vA;
        vA = vB;
        vB = *(const uint4*)(xbase + (unsigned)oC + ebyte);
        oC = csr_off[kk + 6];

        unsigned int cw[4] = {cur.x, cur.y, cur.z, cur.w};
        floatx2 xl2[4];
        floatx2 u2 = (floatx2)0.f;
#pragma unroll
        for (int i = 0; i < 4; ++i) {
            xl2[i] = bf2x2(cw[i]);
            floatx2 t = xl2[i] + xrv2[i];
            t = __builtin_elementwise_max(t, t * NEG_SLOPE);
            u2 += t * attv2[i];
        }
        float u = u2.x + u2.y;
        u += __shfl_xor(u, 1);
        u += __shfl_xor(u, 2);
        float e = __expf(-fabsf(u - m));
        bool kp = (m >= u);
        float sc = kp ? 1.f : e;
        float p  = kp ? e : 1.f;
        m = fmaxf(m, u);
#pragma unroll
        for (int i = 0; i < 4; ++i) acc2[i] = acc2[i] * sc + xl2[i] * p;
        l = fmaf(l, sc, p);
    }
    {
        float mo = __shfl_xor(m, 32);
        float lo = __shfl_xor(l, 32);
        float nm = fmaxf(m, mo);
        float ea = __expf(m - nm);
        float eb = __expf(mo - nm);
#pragma unroll
        for (int i = 0; i < 4; ++i) {
            floatx2 ao = {__shfl_xor(acc2[i].x, 32), __shfl_xor(acc2[i].y, 32)};
            acc2[i] = acc2[i] * ea + ao * eb;
        }
        l = l * ea + lo * eb;
    }
    if (g == 0) {
        float rl = 1.f / (l + 1e-16f);
        short8 o;
#pragma unroll
        for (int i = 0; i < 4; ++i) {
            float v0 = fmaf(acc2[i].x, rl, bias[elem + 2 * i]);
            float v1 = fmaf(acc2[i].y, rl, bias[elem + 2 * i + 1]);
            o[2 * i]     = (short)f2b(fmaxf(v0, 0.f));
            o[2 * i + 1] = (short)f2b(fmaxf(v1, 0.f));
        }
        *(short8*)&h1[(size_t)n * 256 + elem] = o;
    }
}

// ---------------------------------------------------------------------------
// Layer-2 aggregation (unchanged r9): two nodes per wave, 4 slots x 8 lanes
// x 8 ch/lane, fused bias + log_softmax. xlr2: row 256 B; offset = csr>>2.
// ---------------------------------------------------------------------------
__global__ __launch_bounds__(256) void agg2(const ushort* __restrict__ xlr,
                                            const float* __restrict__ att,
                                            const float* __restrict__ bias,
                                            const int* __restrict__ offsets,
                                            const int* __restrict__ csr_off,
                                            float* __restrict__ out, int N)
{
    const int wave = blockIdx.x * 4 + (threadIdx.x >> 6);
    const int lane = threadIdx.x & 63;
    const int n = wave * 2 + (lane >> 5);
    if (n >= N) return;
    const int sub = lane & 31;
    const int g = sub >> 3;
    const int cl = sub & 7;
    const char* __restrict__ xbase = (const char*)xlr;
    const int cbyte = cl * 16;

    floatx2 attv2[4], xrv2[4];
    {
        uint4 xr8 = *(const uint4*)(xbase + (size_t)n * 256 + 128 + cbyte);
        unsigned int xw[4] = {xr8.x, xr8.y, xr8.z, xr8.w};
#pragma unroll
        for (int i = 0; i < 4; ++i) {
            attv2[i] = *(const floatx2*)&att[cl * 8 + 2 * i];
            xrv2[i] = bf2x2(xw[i]);
        }
    }
    float m = -1e30f, l = 0.f;
    floatx2 acc2[4] = {(floatx2)0.f, (floatx2)0.f, (floatx2)0.f, (floatx2)0.f};

    const int beg = offsets[n], end = offsets[n + 1];
    uint4 vA;
    int oB;
    {
        int k0 = beg + g;
        vA = *(const uint4*)(xbase + ((unsigned)csr_off[k0] >> 2) + cbyte);
        oB = csr_off[k0 + 4];
    }
    for (int kk = beg + g; kk < end; kk += 4) {
        uint4 cur = vA;
        vA = *(const uint4*)(xbase + ((unsigned)oB >> 2) + cbyte);
        oB = csr_off[kk + 8];

        unsigned int cw[4] = {cur.x, cur.y, cur.z, cur.w};
        floatx2 xl2[4];
        floatx2 u2 = (floatx2)0.f;
#pragma unroll
        for (int i = 0; i < 4; ++i) {
            xl2[i] = bf2x2(cw[i]);
            floatx2 t = xl2[i] + xrv2[i];
            t = __builtin_elementwise_max(t, t * NEG_SLOPE);
            u2 += t * attv2[i];
        }
        float u = u2.x + u2.y;
        u += __shfl_xor(u, 1);
        u += __shfl_xor(u, 2);
        u += __shfl_xor(u, 4);
        float e = __expf(-fabsf(u - m));
        bool kp = (m >= u);
        float sc = kp ? 1.f : e;
        float p  = kp ? e : 1.f;
        m = fmaxf(m, u);
#pragma unroll
        for (int i = 0; i < 4; ++i) acc2[i] = acc2[i] * sc + xl2[i] * p;
        l = fmaf(l, sc, p);
    }
#pragma unroll
    for (int off = 8; off <= 16; off <<= 1) {
        float mo = __shfl_xor(m, off);
        float lo = __shfl_xor(l, off);
        float nm = fmaxf(m, mo);
        float sa = __expf(m - nm);
        float sb = __expf(mo - nm);
#pragma unroll
        for (int i = 0; i < 4; ++i) {
            floatx2 ao = {__shfl_xor(acc2[i].x, off), __shfl_xor(acc2[i].y, off)};
            acc2[i] = acc2[i] * sa + ao * sb;
        }
        l = l * sa + lo * sb;
        m = nm;
    }
    float rl = 1.f / (l + 1e-16f);
    float h[8];
#pragma unroll
    for (int i = 0; i < 4; ++i) {
        h[2 * i]     = fmaf(acc2[i].x, rl, bias[cl * 8 + 2 * i]);
        h[2 * i + 1] = fmaf(acc2[i].y, rl, bias[cl * 8 + 2 * i + 1]);
    }

    float mx = h[0];
#pragma unroll
    for (int i = 1; i < 8; ++i) mx = fmaxf(mx, h[i]);
    mx = fmaxf(mx, __shfl_xor(mx, 1));
    mx = fmaxf(mx, __shfl_xor(mx, 2));
    mx = fmaxf(mx, __shfl_xor(mx, 4));
    float ssum = 0.f;
#pragma unroll
    for (int i = 0; i < 8; ++i) ssum += __expf(h[i] - mx);
    ssum += __shfl_xor(ssum, 1);
    ssum += __shfl_xor(ssum, 2);
    ssum += __shfl_xor(ssum, 4);
    float lg = mx + __logf(ssum);
    if (g == 0) {
        float4 o0 = make_float4(h[0], h[1], h[2], h[3]);
        float4 o1 = make_float4(h[4], h[5], h[6], h[7]);
        *(float4*)&out[(size_t)n * 64 + cl * 8] = o0;
        *(float4*)&out[(size_t)n * 64 + cl * 8 + 4] = o1;
        float4 s0 = make_float4(h[0] - lg, h[1] - lg, h[2] - lg, h[3] - lg);
        float4 s1 = make_float4(h[4] - lg, h[5] - lg, h[6] - lg, h[7] - lg);
        *(float4*)&out[(size_t)(N + n) * 64 + cl * 8] = s0;
        *(float4*)&out[(size_t)(N + n) * 64 + cl * 8 + 4] = s1;
    }
}

// ---------------------------------------------------------------------------
extern "C" void kernel_launch(void* const* d_in, const int* in_sizes, int n_in,
                              void* d_out, int out_size, void* d_ws, size_t ws_size,
                              hipStream_t stream)
{
    const float* x    = (const float*)d_in[0];
    const int*   ei   = (const int*)d_in[1];
    const float* Wl1  = (const float*)d_in[2];
    const float* Wr1  = (const float*)d_in[3];
    const float* att1 = (const float*)d_in[4];
    const float* b1   = (const float*)d_in[5];
    const float* Wl2  = (const float*)d_in[6];
    const float* Wr2  = (const float*)d_in[7];
    const float* att2 = (const float*)d_in[8];
    const float* b2   = (const float*)d_in[9];
    float* out = (float*)d_out;

    const int F = 256;
    const int E = in_sizes[1] / 2;
    const int N = in_sizes[0] / F;

    const int* e_src = ei;
    const int* e_dst = ei + E;

    // ---- workspace layout ----
    ushort* xb    = (ushort*)d_ws;                   // [N][256] bf16 x
    ushort* wlr1t = xb + (size_t)N * 256;            // [512][256]  (Wl1|Wr1)^T
    ushort* wlr2t = wlr1t + 512 * 256;               // [128][256]  (Wl2|Wr2)^T
    ushort* xlr1  = wlr2t + 128 * 256;               // [N][512]  xl|xr
    ushort* h1b   = xlr1 + (size_t)N * 512;          // [N][256]
    ushort* xlr2  = h1b + (size_t)N * 256;           // [N][128]  xl|xr
    int* offsets  = (int*)(xlr2 + (size_t)N * 128);  // N+1
    int* chunksum = offsets + (N + 1);               // 256
    int* bar      = chunksum + 256;                  // 4 (+pad)
    int* csr_off  = bar + 16;                        // E+16 (byte offsets, padded)
    int* counts16 = csr_off + E + 16;                // N*16 (line-strided)
    int* cursor16 = counts16 + (size_t)N * 16;       // N*16 (line-strided)

    const int XB = (N * 256) / 2048;                 // x-cast blocks (8 elem/thread)

    // ---- barrier counters (16 B) ----
    hipMemsetAsync(bar, 0, 4 * sizeof(int), stream);

    // ---- prep (x cast + weight cast/transpose) ----
    k_prep<<<XB + 640, 256, 0, stream>>>(x, xb, XB, Wl1, Wr1, Wl2, Wr2, wlr1t, wlr2t);

    // ---- layer-1 GEMM ----
    gemm_bf16<128, 128, 256><<<dim3(4, (N + 127) / 128), 256, 0, stream>>>(xb, wlr1t, xlr1, N, 512);

    // ---- fused CSR build (single dispatch, grid barriers) ----
    k_csr<<<CSRG, 256, 0, stream>>>(e_src, e_dst, E, N, counts16, cursor16,
                                    offsets, chunksum, bar, csr_off);

    // ---- layer 1 aggregate ----
    agg1<<<(N + 3) / 4, 256, 0, stream>>>(xlr1, att1, b1, offsets, csr_off, h1b, N);

    // ---- layer 2 ----
    gemm_bf16<128, 64, 256><<<dim3(2, (N + 127) / 128), 256, 0, stream>>>(h1b, wlr2t, xlr2, N, 128);
    agg2<<<(N + 7) / 8, 256, 0, stream>>>(xlr2, att2, b2, offsets, csr_off, out, N);
}